// Round 1
// baseline (405.077 us; speedup 1.0000x reference)
//
#include <hip/hip_runtime.h>
#include <stdint.h>

#define DEV __device__ __forceinline__

using f32x4  = __attribute__((ext_vector_type(4))) float;
using bf16x8 = __attribute__((ext_vector_type(8))) __bf16;
using bf16x4 = __attribute__((ext_vector_type(4))) __bf16;

static constexpr int SEQ  = 2048;
static constexpr int FEA  = 1024;
static constexpr int NHEAD = 16;
static constexpr int NBAT  = 2;
static constexpr int MROWS = NBAT * SEQ;  // 4096
// scale folded into Wq: (1/sqrt(64)) * log2(e)  -> scores directly in exp2 domain
static constexpr float QK_SCALE = 0.18033688011112042f;

DEV f32x4 mfma16(bf16x8 a, bf16x8 b, f32x4 c) {
  return __builtin_amdgcn_mfma_f32_16x16x32_bf16(a, b, c, 0, 0, 0);
}

DEV void gload16(const void* g, void* l) {
  __builtin_amdgcn_global_load_lds((__attribute__((address_space(1))) void*)g,
                                   (__attribute__((address_space(3))) void*)l,
                                   16, 0, 0);
}

// ---------------------------------------------------------------- convert ---
struct ConvSeg { const float* src; __bf16* dst; int n4; float scale; };
struct ConvArgs { ConvSeg seg[7]; };

__global__ __launch_bounds__(256) void convert_k(ConvArgs a) {
  const ConvSeg sg = a.seg[blockIdx.y];
  const int stride = gridDim.x * blockDim.x;
  for (int i = blockIdx.x * blockDim.x + threadIdx.x; i < sg.n4; i += stride) {
    const f32x4 v = *(const f32x4*)(sg.src + (size_t)i * 4);
    bf16x4 o = {(__bf16)(v[0] * sg.scale), (__bf16)(v[1] * sg.scale),
                (__bf16)(v[2] * sg.scale), (__bf16)(v[3] * sg.scale)};
    *(bf16x4*)(sg.dst + (size_t)i * 4) = o;
  }
}

// ------------------------------------------------------------------- GEMM ---
// C[M,N] = A[M,K] @ Bt[N,K]^T  (+bias), 128x128 tile, 4 waves, 16x16x32 bf16.
enum { EPI_HEAD = 0, EPI_VT = 1, EPI_FC = 2 };

template <int EPI>
__global__ __launch_bounds__(256) void gemm_bt(const __bf16* __restrict__ A,
                                               const __bf16* __restrict__ Bt,
                                               const float* __restrict__ bias,
                                               float bscale,
                                               void* __restrict__ outp) {
  __shared__ __align__(16) char lds[16384];
  char* Alds = lds;
  char* Blds = lds + 8192;
  const int tid  = threadIdx.x;
  const int lane = tid & 63;
  const int w    = tid >> 6;
  const int ci   = lane & 15;
  const int g    = lane >> 4;
  const int wr   = w >> 1, wc = w & 1;
  const int row0 = blockIdx.x * 128;
  const int col0 = blockIdx.y * 128;
  constexpr int K = 1024;

  // staging chunks: 512 chunks of 16B per matrix per K-step (128 rows x 64B)
  const int c0 = tid, c1 = tid + 256;
  const __bf16* ga0 = A  + (size_t)(row0 + (c0 >> 2)) * K + (c0 & 3) * 8;
  const __bf16* ga1 = A  + (size_t)(row0 + (c1 >> 2)) * K + (c1 & 3) * 8;
  const __bf16* gb0 = Bt + (size_t)(col0 + (c0 >> 2)) * K + (c0 & 3) * 8;
  const __bf16* gb1 = Bt + (size_t)(col0 + (c1 >> 2)) * K + (c1 & 3) * 8;
  char* la0 = Alds + c0 * 16;
  char* la1 = Alds + c1 * 16;
  char* lb0 = Blds + c0 * 16;
  char* lb1 = Blds + c1 * 16;

  f32x4 acc[4][4] = {};

  for (int k0 = 0; k0 < K; k0 += 32) {
    __syncthreads();                       // previous compute done, LDS free
    gload16(ga0 + k0, la0);
    gload16(ga1 + k0, la1);
    gload16(gb0 + k0, lb0);
    gload16(gb1 + k0, lb1);
    __syncthreads();                       // compiler drains vmcnt before barrier
    bf16x8 af[4], bfr[4];
#pragma unroll
    for (int m = 0; m < 4; ++m)
      af[m] = *(const bf16x8*)(Alds + ((wr * 64 + m * 16 + ci) * 32 + g * 8) * 2);
#pragma unroll
    for (int n = 0; n < 4; ++n)
      bfr[n] = *(const bf16x8*)(Blds + ((wc * 64 + n * 16 + ci) * 32 + g * 8) * 2);
#pragma unroll
    for (int m = 0; m < 4; ++m)
#pragma unroll
      for (int n = 0; n < 4; ++n)
        acc[m][n] = mfma16(af[m], bfr[n], acc[m][n]);
  }

#pragma unroll
  for (int m = 0; m < 4; ++m)
#pragma unroll
    for (int n = 0; n < 4; ++n)
#pragma unroll
      for (int r = 0; r < 4; ++r) {
        const int gr = row0 + wr * 64 + m * 16 + 4 * g + r;  // M row
        const int gc = col0 + wc * 64 + n * 16 + ci;         // N col
        float vv = acc[m][n][r] + bias[gc] * bscale;
        if constexpr (EPI == EPI_FC) {
          ((float*)outp)[(size_t)gr * FEA + gc] = fmaxf(vv, 0.0f);
        } else {
          const int b = gr >> 11, s = gr & (SEQ - 1);
          const int h = gc >> 6,  d = gc & 63;
          if constexpr (EPI == EPI_HEAD) {   // [B,H,S,D]
            ((__bf16*)outp)[(((size_t)b * NHEAD + h) * SEQ + s) * 64 + d] = (__bf16)vv;
          } else {                           // [B,H,D,S]
            ((__bf16*)outp)[(((size_t)b * NHEAD + h) * 64 + d) * SEQ + s] = (__bf16)vv;
          }
        }
      }
}

// -------------------------------------------------------------- attention ---
// One block = 16 q-rows of one (b,h). 512 thr (8 waves).
// Phase A: S=Q*K^T (exp2-domain), E=exp2(S) -> LDS bf16 (XOR swizzled), rowsums.
// Phase B: attn_out = E/rowsum (fp32, coalesced float4).
// Phase C: ctx = (E @ V)/rowsum -> Cbuf bf16 [B,S,F].
__global__ __launch_bounds__(512, 4) void attn_fused(const __bf16* __restrict__ Qh,
                                                     const __bf16* __restrict__ Kh,
                                                     const __bf16* __restrict__ VhT,
                                                     float* __restrict__ attn_out,
                                                     __bf16* __restrict__ Cbuf) {
  __shared__ __align__(16) char Elds[16 * 4096];  // 16 rows x 2048 bf16, swizzled
  __shared__ float rs_lds[8][16];
  __shared__ float inv_lds[16];
  __shared__ float pv_lds[4][16][16];

  const int tid  = threadIdx.x;
  const int lane = tid & 63;
  const int w    = tid >> 6;
  const int ci   = lane & 15;
  const int g    = lane >> 4;

  // XCD-aware swizzle: each XCD (id&7) owns 4 heads -> K/V working set 2MB < L2
  const int id   = blockIdx.x;
  const int xcd  = id & 7;
  const int idx  = id >> 3;
  const int bh   = xcd * 4 + (idx >> 7);
  const int qblk = idx & 127;

  const __bf16* Qp = Qh  + ((size_t)bh * SEQ + qblk * 16) * 64;
  const __bf16* Kp = Kh  + (size_t)bh * SEQ * 64;
  const __bf16* Vp = VhT + (size_t)bh * 64 * SEQ;

  // Q fragments (rows ci, k-dim split 2x32)
  const bf16x8 aq0 = *(const bf16x8*)(Qp + ci * 64 + 8 * g);
  const bf16x8 aq1 = *(const bf16x8*)(Qp + ci * 64 + 32 + 8 * g);

  float rs[4] = {0.f, 0.f, 0.f, 0.f};
  for (int it = 0; it < 16; ++it) {
    const int kcol = it * 128 + w * 16;
    const __bf16* kp = Kp + (size_t)(kcol + ci) * 64 + 8 * g;
    const bf16x8 bk0 = *(const bf16x8*)(kp);
    const bf16x8 bk1 = *(const bf16x8*)(kp + 32);
    f32x4 sf = {0.f, 0.f, 0.f, 0.f};
    sf = mfma16(aq0, bk0, sf);
    sf = mfma16(aq1, bk1, sf);
#pragma unroll
    for (int r = 0; r < 4; ++r) {
      const float e = exp2f(sf[r]);        // D row = q = 4g+r, col = kcol+ci
      rs[r] += e;
      const int qq = 4 * g + r;
      const int byt = qq * 4096 + ((((kcol + ci) * 2)) ^ ((qq & 7) << 4));
      *(__bf16*)(Elds + byt) = (__bf16)e;
    }
  }
  // reduce rowsums over the 16 k-col lanes (lane bits 0..3)
#pragma unroll
  for (int mm = 1; mm < 16; mm <<= 1) {
#pragma unroll
    for (int r = 0; r < 4; ++r) rs[r] += __shfl_xor(rs[r], mm);
  }
  if (ci == 0) {
#pragma unroll
    for (int r = 0; r < 4; ++r) rs_lds[w][4 * g + r] = rs[r];
  }
  __syncthreads();
  if (tid < 16) {
    float t = 0.f;
#pragma unroll
    for (int ww = 0; ww < 8; ++ww) t += rs_lds[ww][tid];
    inv_lds[tid] = 1.0f / t;
  }
  __syncthreads();

  // Phase B: normalized attn, coalesced float4 stores
  {
    const int qq = tid >> 5;
    const int cc = (tid & 31) * 4;
    const float inv = inv_lds[qq];
    float* orow = attn_out + ((size_t)bh * SEQ + qblk * 16 + qq) * SEQ;
#pragma unroll
    for (int i = 0; i < 16; ++i) {
      const int col = cc + i * 128;
      const int byt = qq * 4096 + (((col * 2)) ^ ((qq & 7) << 4));
      const bf16x4 ev = *(const bf16x4*)(Elds + byt);
      f32x4 o = {(float)ev[0] * inv, (float)ev[1] * inv,
                 (float)ev[2] * inv, (float)ev[3] * inv};
      *(f32x4*)(orow + col) = o;
    }
  }

  // Phase C: PV. wave -> d-tile (w&3), k-half (w>>2)
  const int dt = w & 3, kh2 = w >> 2;
  f32x4 apv = {0.f, 0.f, 0.f, 0.f};
  const __bf16* vp = Vp + (size_t)(dt * 16 + ci) * SEQ + kh2 * 1024 + 8 * g;
#pragma unroll 4
  for (int kt = 0; kt < 32; ++kt) {
    const int k0 = kh2 * 1024 + kt * 32;
    const int byt = ci * 4096 + ((((k0 + 8 * g) * 2)) ^ ((ci & 7) << 4));
    const bf16x8 pa = *(const bf16x8*)(Elds + byt);   // E row ci, cols k0+8g..
    const bf16x8 vb = *(const bf16x8*)(vp + kt * 32); // VhT row dt*16+ci
    apv = mfma16(pa, vb, apv);
  }
  if (w >= 4) {
#pragma unroll
    for (int r = 0; r < 4; ++r) pv_lds[dt][4 * g + r][ci] = apv[r];
  }
  __syncthreads();
  if (w < 4) {
    const int b = bh >> 4, h = bh & 15;
#pragma unroll
    for (int r = 0; r < 4; ++r) {
      const int qq = 4 * g + r;
      const float vv = (apv[r] + pv_lds[dt][qq][ci]) * inv_lds[qq];
      Cbuf[((size_t)b * SEQ + qblk * 16 + qq) * FEA + h * 64 + dt * 16 + ci] = (__bf16)vv;
    }
  }
}

// ------------------------------------------------------------------ launch ---
extern "C" void kernel_launch(void* const* d_in, const int* in_sizes, int n_in,
                              void* d_out, int out_size, void* d_ws, size_t ws_size,
                              hipStream_t stream) {
  const float* q    = (const float*)d_in[0];
  const float* k    = (const float*)d_in[1];
  const float* v    = (const float*)d_in[2];
  const float* wq_w = (const float*)d_in[3];
  const float* wq_b = (const float*)d_in[4];
  const float* wk_w = (const float*)d_in[5];
  const float* wk_b = (const float*)d_in[6];
  const float* wv_w = (const float*)d_in[7];
  const float* wv_b = (const float*)d_in[8];
  const float* fc_w = (const float*)d_in[9];
  const float* fc_b = (const float*)d_in[10];

  float* out0 = (float*)d_out;
  float* attn = out0 + (size_t)MROWS * FEA;  // second tuple output

  // bf16 scratch that dies before attn runs -> reuse the attn output region
  __bf16* Xq = (__bf16*)attn;
  __bf16* Xk = Xq + (size_t)MROWS * FEA;
  __bf16* Xv = Xk + (size_t)MROWS * FEA;
  __bf16* Wq = Xv + (size_t)MROWS * FEA;
  __bf16* Wk = Wq + (size_t)FEA * FEA;
  __bf16* Wv = Wk + (size_t)FEA * FEA;

  // persistent scratch (lives across attn) -> d_ws, 34 MiB
  __bf16* Qh  = (__bf16*)d_ws;
  __bf16* Kh  = Qh  + (size_t)MROWS * 64 * NHEAD / NHEAD * 1;  // 4M elems each
  Kh = Qh + (size_t)MROWS * FEA;  // keep it simple: 4,194,304 elems
  __bf16* VhT = Kh + (size_t)MROWS * FEA;
  __bf16* Cb  = VhT + (size_t)MROWS * FEA;
  __bf16* Wfc = Cb + (size_t)MROWS * FEA;

  ConvArgs ca;
  ca.seg[0] = {q,    Xq,  (MROWS * FEA) / 4, 1.0f};
  ca.seg[1] = {k,    Xk,  (MROWS * FEA) / 4, 1.0f};
  ca.seg[2] = {v,    Xv,  (MROWS * FEA) / 4, 1.0f};
  ca.seg[3] = {wq_w, Wq,  (FEA * FEA) / 4,   QK_SCALE};
  ca.seg[4] = {wk_w, Wk,  (FEA * FEA) / 4,   1.0f};
  ca.seg[5] = {wv_w, Wv,  (FEA * FEA) / 4,   1.0f};
  ca.seg[6] = {fc_w, Wfc, (FEA * FEA) / 4,   1.0f};
  convert_k<<<dim3(512, 7), 256, 0, stream>>>(ca);

  dim3 gg(MROWS / 128, FEA / 128);  // 32 x 8
  gemm_bt<EPI_HEAD><<<gg, 256, 0, stream>>>(Xq, Wq, wq_b, QK_SCALE, Qh);
  gemm_bt<EPI_HEAD><<<gg, 256, 0, stream>>>(Xk, Wk, wk_b, 1.0f, Kh);
  gemm_bt<EPI_VT  ><<<gg, 256, 0, stream>>>(Xv, Wv, wv_b, 1.0f, VhT);

  attn_fused<<<dim3(4096), 512, 0, stream>>>(Qh, Kh, VhT, attn, Cb);

  gemm_bt<EPI_FC><<<gg, 256, 0, stream>>>(Cb, Wfc, fc_b, 1.0f, out0);
}

// Round 2
// 340.898 us; speedup vs baseline: 1.1883x; 1.1883x over previous
//
#include <hip/hip_runtime.h>
#include <stdint.h>

#define DEV __device__ __forceinline__

using f32x4  = __attribute__((ext_vector_type(4))) float;
using bf16x8 = __attribute__((ext_vector_type(8))) __bf16;
using bf16x4 = __attribute__((ext_vector_type(4))) __bf16;

static constexpr int SEQ  = 2048;
static constexpr int FEA  = 1024;
static constexpr int NHEAD = 16;
static constexpr int MROWS = 4096;  // B*S
// scale folded into Wq: (1/sqrt(64)) * log2(e)  -> scores directly in exp2 domain
static constexpr float QK_SCALE = 0.18033688011112042f;

DEV f32x4 mfma16(bf16x8 a, bf16x8 b, f32x4 c) {
  return __builtin_amdgcn_mfma_f32_16x16x32_bf16(a, b, c, 0, 0, 0);
}

DEV void gload16(const void* g, void* l) {
  __builtin_amdgcn_global_load_lds((__attribute__((address_space(1))) void*)g,
                                   (__attribute__((address_space(3))) void*)l,
                                   16, 0, 0);
}

// ---------------------------------------------------------------- convert ---
struct ConvSeg { const float* src; __bf16* dst; int n4; float scale; };
struct ConvArgs { ConvSeg seg[7]; };

__global__ __launch_bounds__(256) void convert_k(ConvArgs a) {
  const ConvSeg sg = a.seg[blockIdx.y];
  const int stride = gridDim.x * blockDim.x;
  for (int i = blockIdx.x * blockDim.x + threadIdx.x; i < sg.n4; i += stride) {
    const f32x4 v = *(const f32x4*)(sg.src + (size_t)i * 4);
    bf16x4 o = {(__bf16)(v[0] * sg.scale), (__bf16)(v[1] * sg.scale),
                (__bf16)(v[2] * sg.scale), (__bf16)(v[3] * sg.scale)};
    *(bf16x4*)(sg.dst + (size_t)i * 4) = o;
  }
}

// ------------------------------------------------------------------- GEMM ---
// Shared 128x128-tile, 4-wave, 16x16x32 bf16 main loop (m97 structure).
DEV void gemm_core(const __bf16* __restrict__ A, const __bf16* __restrict__ Bt,
                   char* lds, int row0, int col0, int tid, f32x4 (&acc)[4][4]) {
  char* Alds = lds;
  char* Blds = lds + 8192;
  constexpr int K = 1024;
  const int lane = tid & 63;
  const int w    = tid >> 6;
  const int ci   = lane & 15;
  const int g    = lane >> 4;
  const int wr   = w >> 1, wc = w & 1;

  const int c0 = tid, c1 = tid + 256;
  const __bf16* ga0 = A  + (size_t)(row0 + (c0 >> 2)) * K + (c0 & 3) * 8;
  const __bf16* ga1 = A  + (size_t)(row0 + (c1 >> 2)) * K + (c1 & 3) * 8;
  const __bf16* gb0 = Bt + (size_t)(col0 + (c0 >> 2)) * K + (c0 & 3) * 8;
  const __bf16* gb1 = Bt + (size_t)(col0 + (c1 >> 2)) * K + (c1 & 3) * 8;
  char* la0 = Alds + c0 * 16;
  char* la1 = Alds + c1 * 16;
  char* lb0 = Blds + c0 * 16;
  char* lb1 = Blds + c1 * 16;

  for (int k0 = 0; k0 < K; k0 += 32) {
    __syncthreads();
    gload16(ga0 + k0, la0);
    gload16(ga1 + k0, la1);
    gload16(gb0 + k0, lb0);
    gload16(gb1 + k0, lb1);
    __syncthreads();
    bf16x8 af[4], bfr[4];
#pragma unroll
    for (int m = 0; m < 4; ++m)
      af[m] = *(const bf16x8*)(Alds + ((wr * 64 + m * 16 + ci) * 32 + g * 8) * 2);
#pragma unroll
    for (int n = 0; n < 4; ++n)
      bfr[n] = *(const bf16x8*)(Blds + ((wc * 64 + n * 16 + ci) * 32 + g * 8) * 2);
#pragma unroll
    for (int m = 0; m < 4; ++m)
#pragma unroll
      for (int n = 0; n < 4; ++n)
        acc[m][n] = mfma16(af[m], bfr[n], acc[m][n]);
  }
}

// Batched q/k/v projection: grid.z picks the problem. z=0,1 -> [B,H,S,D]; z=2 -> [B,H,D,S].
struct QkvArgs {
  const __bf16* A[3];
  const __bf16* Bt[3];
  const float*  bias[3];
  float         bscale[3];
  __bf16*       out[3];
};

__global__ __launch_bounds__(256) void gemm_qkv(QkvArgs args) {
  __shared__ __align__(16) char lds[16384];
  const int z = blockIdx.z;
  const int tid = threadIdx.x;
  const int row0 = blockIdx.x * 128;
  const int col0 = blockIdx.y * 128;
  f32x4 acc[4][4] = {};
  gemm_core(args.A[z], args.Bt[z], lds, row0, col0, tid, acc);

  const int lane = tid & 63;
  const int ci = lane & 15, g = lane >> 4;
  const int w = tid >> 6;
  const int wr = w >> 1, wc = w & 1;
  const float* bias = args.bias[z];
  const float bscale = args.bscale[z];
  __bf16* outp = args.out[z];
  const bool vt = (z == 2);
#pragma unroll
  for (int m = 0; m < 4; ++m)
#pragma unroll
    for (int n = 0; n < 4; ++n)
#pragma unroll
      for (int r = 0; r < 4; ++r) {
        const int gr = row0 + wr * 64 + m * 16 + 4 * g + r;
        const int gc = col0 + wc * 64 + n * 16 + ci;
        const float vv = acc[m][n][r] + bias[gc] * bscale;
        const int b = gr >> 11, s = gr & (SEQ - 1);
        const int h = gc >> 6,  d = gc & 63;
        if (!vt)
          outp[(((size_t)b * NHEAD + h) * SEQ + s) * 64 + d] = (__bf16)vv;
        else
          outp[(((size_t)b * NHEAD + h) * 64 + d) * SEQ + s] = (__bf16)vv;
      }
}

__global__ __launch_bounds__(256) void gemm_fc(const __bf16* __restrict__ A,
                                               const __bf16* __restrict__ Bt,
                                               const float* __restrict__ bias,
                                               float* __restrict__ outp) {
  __shared__ __align__(16) char lds[16384];
  const int tid = threadIdx.x;
  const int row0 = blockIdx.x * 128;
  const int col0 = blockIdx.y * 128;
  f32x4 acc[4][4] = {};
  gemm_core(A, Bt, lds, row0, col0, tid, acc);

  const int lane = tid & 63;
  const int ci = lane & 15, g = lane >> 4;
  const int w = tid >> 6;
  const int wr = w >> 1, wc = w & 1;
#pragma unroll
  for (int m = 0; m < 4; ++m)
#pragma unroll
    for (int n = 0; n < 4; ++n)
#pragma unroll
      for (int r = 0; r < 4; ++r) {
        const int gr = row0 + wr * 64 + m * 16 + 4 * g + r;
        const int gc = col0 + wc * 64 + n * 16 + ci;
        const float vv = fmaxf(acc[m][n][r] + bias[gc], 0.0f);
        __builtin_nontemporal_store(vv, &outp[(size_t)gr * FEA + gc]);
      }
}

// -------------------------------------------------------------- attention ---
// One block = 16 q-rows of one (b,h). 512 thr (8 waves).
// Phase A: swapped QK^T (mfma(K,Q)) in exp2-domain -> lane owns q-row ci with
//          4 consecutive k-cols per reg -> vectorized bf16x4 E stores (XOR swz).
// Phase B: attn_out = E/rowsum (fp32, coalesced nontemporal float4).
// Phase C: ctx = (E @ V)/rowsum -> Cbuf bf16 [B,S,F].
__global__ __launch_bounds__(512, 4) void attn_fused(const __bf16* __restrict__ Qh,
                                                     const __bf16* __restrict__ Kh,
                                                     const __bf16* __restrict__ VhT,
                                                     float* __restrict__ attn_out,
                                                     __bf16* __restrict__ Cbuf) {
  __shared__ __align__(16) char Elds[16 * 4096];  // 16 rows x 2048 bf16, swizzled
  __shared__ float rs_lds[8][16];
  __shared__ float inv_lds[16];
  __shared__ float pv_lds[4][16][16];

  const int tid  = threadIdx.x;
  const int lane = tid & 63;
  const int w    = tid >> 6;
  const int ci   = lane & 15;
  const int g    = lane >> 4;

  // XCD-aware swizzle: each XCD (id&7) owns 4 heads -> K/V working set 2MB < L2
  const int id   = blockIdx.x;
  const int xcd  = id & 7;
  const int idx  = id >> 3;
  const int bh   = xcd * 4 + (idx >> 7);
  const int qblk = idx & 127;

  const __bf16* Qp = Qh  + ((size_t)bh * SEQ + qblk * 16) * 64;
  const __bf16* Kp = Kh  + (size_t)bh * SEQ * 64;
  const __bf16* Vp = VhT + (size_t)bh * 64 * SEQ;

  // Q fragments (rows ci, k-dim split 2x32) -- used as MFMA *B* operand
  const bf16x8 aq0 = *(const bf16x8*)(Qp + ci * 64 + 8 * g);
  const bf16x8 aq1 = *(const bf16x8*)(Qp + ci * 64 + 32 + 8 * g);

  float rs = 0.f;
#pragma unroll 4
  for (int it = 0; it < 16; ++it) {
    const int kcol = it * 128 + w * 16;
    const __bf16* kp = Kp + (size_t)(kcol + ci) * 64 + 8 * g;
    const bf16x8 bk0 = *(const bf16x8*)(kp);
    const bf16x8 bk1 = *(const bf16x8*)(kp + 32);
    f32x4 sf = {0.f, 0.f, 0.f, 0.f};
    sf = mfma16(bk0, aq0, sf);   // swapped: D[k-off][q], lane: q=ci, k=kcol+4g+r
    sf = mfma16(bk1, aq1, sf);
    bf16x4 ev;
#pragma unroll
    for (int r = 0; r < 4; ++r) {
      const float e = __builtin_amdgcn_exp2f(sf[r]);
      rs += e;
      ev[r] = (__bf16)e;
    }
    const int col0 = kcol + 4 * g;
    *(bf16x4*)(Elds + ci * 4096 + ((col0 * 2) ^ ((ci & 7) << 4))) = ev;
  }
  // lane holds partial rowsum for q=ci over its g-subset; reduce over g (bits 4,5)
  rs += __shfl_xor(rs, 16);
  rs += __shfl_xor(rs, 32);
  if (lane < 16) rs_lds[w][lane] = rs;
  __syncthreads();
  if (tid < 16) {
    float t = 0.f;
#pragma unroll
    for (int ww = 0; ww < 8; ++ww) t += rs_lds[ww][tid];
    inv_lds[tid] = 1.0f / t;
  }
  __syncthreads();

  // Phase B: normalized attn, coalesced nontemporal float4 stores
  {
    const int qq = tid >> 5;
    const int cc = (tid & 31) * 4;
    const float inv = inv_lds[qq];
    float* orow = attn_out + ((size_t)bh * SEQ + qblk * 16 + qq) * SEQ;
#pragma unroll
    for (int i = 0; i < 16; ++i) {
      const int col = cc + i * 128;
      const int byt = qq * 4096 + (((col * 2)) ^ ((qq & 7) << 4));
      const bf16x4 ev = *(const bf16x4*)(Elds + byt);
      f32x4 o = {(float)ev[0] * inv, (float)ev[1] * inv,
                 (float)ev[2] * inv, (float)ev[3] * inv};
      __builtin_nontemporal_store(o, (f32x4*)(orow + col));
    }
  }

  // Phase C: PV. wave -> d-tile (w&3), k-half (w>>2)
  const int dt = w & 3, kh2 = w >> 2;
  f32x4 apv = {0.f, 0.f, 0.f, 0.f};
  const __bf16* vp = Vp + (size_t)(dt * 16 + ci) * SEQ + kh2 * 1024 + 8 * g;
#pragma unroll 4
  for (int kt = 0; kt < 32; ++kt) {
    const int k0 = kh2 * 1024 + kt * 32;
    const int byt = ci * 4096 + ((((k0 + 8 * g) * 2)) ^ ((ci & 7) << 4));
    const bf16x8 pa = *(const bf16x8*)(Elds + byt);   // E row ci, cols k0+8g..
    const bf16x8 vb = *(const bf16x8*)(vp + kt * 32); // VhT row dt*16+ci
    apv = mfma16(pa, vb, apv);
  }
  if (w >= 4) {
#pragma unroll
    for (int r = 0; r < 4; ++r) pv_lds[dt][4 * g + r][ci] = apv[r];
  }
  __syncthreads();
  if (w < 4) {
    const int b = bh >> 4, h = bh & 15;
#pragma unroll
    for (int r = 0; r < 4; ++r) {
      const int qq = 4 * g + r;
      const float vv = (apv[r] + pv_lds[dt][qq][ci]) * inv_lds[qq];
      Cbuf[((size_t)b * SEQ + qblk * 16 + qq) * FEA + h * 64 + dt * 16 + ci] = (__bf16)vv;
    }
  }
}

// ------------------------------------------------------------------ launch ---
extern "C" void kernel_launch(void* const* d_in, const int* in_sizes, int n_in,
                              void* d_out, int out_size, void* d_ws, size_t ws_size,
                              hipStream_t stream) {
  const float* q    = (const float*)d_in[0];
  const float* k    = (const float*)d_in[1];
  const float* v    = (const float*)d_in[2];
  const float* wq_w = (const float*)d_in[3];
  const float* wq_b = (const float*)d_in[4];
  const float* wk_w = (const float*)d_in[5];
  const float* wk_b = (const float*)d_in[6];
  const float* wv_w = (const float*)d_in[7];
  const float* wv_b = (const float*)d_in[8];
  const float* fc_w = (const float*)d_in[9];
  const float* fc_b = (const float*)d_in[10];

  float* out0 = (float*)d_out;
  float* attn = out0 + (size_t)MROWS * FEA;  // second tuple output

  // bf16 scratch that dies before attn runs -> reuse the attn output region
  __bf16* Xq = (__bf16*)attn;
  __bf16* Xk = Xq + (size_t)MROWS * FEA;
  __bf16* Xv = Xk + (size_t)MROWS * FEA;
  __bf16* Wq = Xv + (size_t)MROWS * FEA;
  __bf16* Wk = Wq + (size_t)FEA * FEA;
  __bf16* Wv = Wk + (size_t)FEA * FEA;

  // persistent scratch (lives across attn) -> d_ws, 34 MiB
  __bf16* Qh  = (__bf16*)d_ws;
  __bf16* Kh  = Qh  + (size_t)MROWS * FEA;
  __bf16* VhT = Kh  + (size_t)MROWS * FEA;
  __bf16* Cb  = VhT + (size_t)MROWS * FEA;
  __bf16* Wfc = Cb  + (size_t)MROWS * FEA;

  ConvArgs ca;
  ca.seg[0] = {q,    Xq,  (MROWS * FEA) / 4, 1.0f};
  ca.seg[1] = {k,    Xk,  (MROWS * FEA) / 4, 1.0f};
  ca.seg[2] = {v,    Xv,  (MROWS * FEA) / 4, 1.0f};
  ca.seg[3] = {wq_w, Wq,  (FEA * FEA) / 4,   QK_SCALE};
  ca.seg[4] = {wk_w, Wk,  (FEA * FEA) / 4,   1.0f};
  ca.seg[5] = {wv_w, Wv,  (FEA * FEA) / 4,   1.0f};
  ca.seg[6] = {fc_w, Wfc, (FEA * FEA) / 4,   1.0f};
  convert_k<<<dim3(512, 7), 256, 0, stream>>>(ca);

  QkvArgs qa;
  qa.A[0] = Xq; qa.Bt[0] = Wq; qa.bias[0] = wq_b; qa.bscale[0] = QK_SCALE; qa.out[0] = Qh;
  qa.A[1] = Xk; qa.Bt[1] = Wk; qa.bias[1] = wk_b; qa.bscale[1] = 1.0f;     qa.out[1] = Kh;
  qa.A[2] = Xv; qa.Bt[2] = Wv; qa.bias[2] = wv_b; qa.bscale[2] = 1.0f;     qa.out[2] = VhT;
  gemm_qkv<<<dim3(MROWS / 128, FEA / 128, 3), 256, 0, stream>>>(qa);

  attn_fused<<<dim3(4096), 512, 0, stream>>>(Qh, Kh, VhT, attn, Cb);

  gemm_fc<<<dim3(MROWS / 128, FEA / 128), 256, 0, stream>>>(Cb, Wfc, fc_b, out0);
}